// Round 5
// baseline (1439.479 us; speedup 1.0000x reference)
//
#include <hip/hip_runtime.h>
#include <cstddef>

#define TT 256
#define HH 128
#define EST 132   // staging stride for enc_proj (prologue only)

// Prologue staging (enc_proj, 135168 B) overlaps the steady-state big arrays.
union __align__(16) SMU {
  float stage[TT * EST];               // 33792 floats
  struct {
    float w2[HH * HH];                 // 16384 : W2[j][k] row-major
    float part[8 * HH];                // 1024  : phase-C partials
    float zpart[512];                  // 512   : phase-A upper-half partials
    float scp[16 * 257];               // 4112  : phase-D partials (padded stride)
  } s;                                 // 22032 floats < 33792
};

__device__ __forceinline__ float rdlane(float v, int l) {
  return __int_as_float(__builtin_amdgcn_readlane(__float_as_int(v), l));
}
__device__ __forceinline__ float fast_sigmoid(float x) {
  const float L2E = 1.4426950408889634f;
  float y = __builtin_amdgcn_exp2f(-x * L2E);
  return __builtin_amdgcn_rcpf(1.0f + y);
}
__device__ __forceinline__ float fast_tanh(float x) {
  const float C2 = 2.8853900817779268f;   // 2*log2(e)
  float y = __builtin_amdgcn_exp2f(x * C2);
  return 1.0f - 2.0f * __builtin_amdgcn_rcpf(1.0f + y);
}

// One workgroup per batch element; 1024 threads = 16 waves (4/SIMD).
// E=exp2(C2*enc_proj) in REGISTERS (32/thread); Wr half-column in regs (64);
// phase D: 3 VALU/term, (U,v2) via wave-uniform broadcast ds_read_b128.
__global__ __launch_bounds__(1024)
void decoder_kernel(const float* __restrict__ x,
                    const float* __restrict__ enc_output,
                    const float* __restrict__ h0,
                    const float* __restrict__ c0,
                    const float* __restrict__ W1,
                    const float* __restrict__ W2,
                    const float* __restrict__ V,
                    const float* __restrict__ Wk,
                    const float* __restrict__ Wr,
                    const float* __restrict__ bias,
                    float* __restrict__ out)
{
  __shared__ SMU sm;
  __shared__ float hbuf[HH];
  __shared__ float xloc[TT * 2];
  __shared__ float uvl[2 * HH];        // uvl[2k]=U_k (per step), uvl[2k+1]=-2V[k]
  __shared__ float amax_s[4];
  __shared__ int   amax_t[4];
  __shared__ float ssum[4];

  const int u    = threadIdx.x;
  const int b    = blockIdx.x;
  const int lane = u & 63;
  const int w    = u >> 6;             // wave 0..15 (phase-D k-octet owner)
  const float C2  = 2.8853900817779268f;
  const float L2E = 1.4426950408889634f;

  // ---------------- P0: enc_proj = enc_output[b] @ W1 -> staging ----------------
  {
    const float* encb = enc_output + (size_t)b * TT * HH;
    const int tsub = u >> 4;           // 0..63
    const int ks   = (u & 15) * 8;
    for (int p = 0; p < 4; ++p) {
      const int tt = p * 64 + tsub;
      float4 a0 = {0.f, 0.f, 0.f, 0.f};
      float4 a1 = {0.f, 0.f, 0.f, 0.f};
      const float4* er4 = (const float4*)(encb + tt * HH);
      for (int j4 = 0; j4 < 32; ++j4) {
        const float4 ev = er4[j4];
        const float* w1p = W1 + (j4 * 4) * HH + ks;
        float4 wa, wb;
        wa = *(const float4*)(w1p + 0 * HH); wb = *(const float4*)(w1p + 0 * HH + 4);
        a0.x += ev.x * wa.x; a0.y += ev.x * wa.y; a0.z += ev.x * wa.z; a0.w += ev.x * wa.w;
        a1.x += ev.x * wb.x; a1.y += ev.x * wb.y; a1.z += ev.x * wb.z; a1.w += ev.x * wb.w;
        wa = *(const float4*)(w1p + 1 * HH); wb = *(const float4*)(w1p + 1 * HH + 4);
        a0.x += ev.y * wa.x; a0.y += ev.y * wa.y; a0.z += ev.y * wa.z; a0.w += ev.y * wa.w;
        a1.x += ev.y * wb.x; a1.y += ev.y * wb.y; a1.z += ev.y * wb.z; a1.w += ev.y * wb.w;
        wa = *(const float4*)(w1p + 2 * HH); wb = *(const float4*)(w1p + 2 * HH + 4);
        a0.x += ev.z * wa.x; a0.y += ev.z * wa.y; a0.z += ev.z * wa.z; a0.w += ev.z * wa.w;
        a1.x += ev.z * wb.x; a1.y += ev.z * wb.y; a1.z += ev.z * wb.z; a1.w += ev.z * wb.w;
        wa = *(const float4*)(w1p + 3 * HH); wb = *(const float4*)(w1p + 3 * HH + 4);
        a0.x += ev.w * wa.x; a0.y += ev.w * wa.y; a0.z += ev.w * wa.z; a0.w += ev.w * wa.w;
        a1.x += ev.w * wb.x; a1.y += ev.w * wb.y; a1.z += ev.w * wb.z; a1.w += ev.w * wb.w;
      }
      *(float4*)(&sm.stage[tt * EST + ks])     = a0;
      *(float4*)(&sm.stage[tt * EST + ks + 4]) = a1;
    }
  }
  __syncthreads();   // staging complete

  // ---------------- P1: E regs. thread: rows t=64i+lane (i<4), cols 8w..8w+8 ----
  float Ereg[32];
  {
    #pragma unroll
    for (int i = 0; i < 4; ++i) {
      const float* sp = &sm.stage[(64 * i + lane) * EST + 8 * w];
      float4 e0 = *(const float4*)sp;
      float4 e1 = *(const float4*)(sp + 4);
      Ereg[8*i + 0] = __builtin_amdgcn_exp2f(e0.x * C2);
      Ereg[8*i + 1] = __builtin_amdgcn_exp2f(e0.y * C2);
      Ereg[8*i + 2] = __builtin_amdgcn_exp2f(e0.z * C2);
      Ereg[8*i + 3] = __builtin_amdgcn_exp2f(e0.w * C2);
      Ereg[8*i + 4] = __builtin_amdgcn_exp2f(e1.x * C2);
      Ereg[8*i + 5] = __builtin_amdgcn_exp2f(e1.y * C2);
      Ereg[8*i + 6] = __builtin_amdgcn_exp2f(e1.z * C2);
      Ereg[8*i + 7] = __builtin_amdgcn_exp2f(e1.w * C2);
    }
  }
  __syncthreads();   // staging reads done; union region reusable

  // ---------------- P2: steady LDS init (overwrites staging region) ----------------
  {
    const float4* w2g = (const float4*)W2;     // 4096 float4
    float4* w2l = (float4*)sm.s.w2;
    #pragma unroll
    for (int i = 0; i < 4; ++i) w2l[u + 1024 * i] = w2g[u + 1024 * i];
    if (u < 512) xloc[u] = x[b * (TT * 2) + u];
    else         xloc[u - 512] = x[b * (TT * 2) + (u - 512)];   // (redundant-safe)
    if (u < HH) {
      hbuf[u] = h0[b * HH + u];
      uvl[2 * u + 1] = -2.0f * V[u];
    }
  }

  // ---------------- persistent registers ----------------
  const int uu  = u & 511;             // phase-A column id
  const int g   = uu & 3;              // LSTM gate
  const int m   = uu >> 2;             // LSTM unit
  const int col = g * HH + m;
  const int kh  = u >> 9;              // 0: ptr+h[0:64), 1: h[64:128)+bias
  float wrreg[64];
  #pragma unroll
  for (int i = 0; i < 64; ++i) wrreg[i] = Wr[(64 * kh + i) * 512 + col];
  float ra0, ra1;
  if (kh == 0) { ra0 = Wk[col]; ra1 = Wk[512 + col]; }
  else         { ra0 = bias[col]; ra1 = 0.0f; }
  float c = (u < 512) ? c0[b * HH + m] : 0.0f;
  float ptr0 = 1.0f, ptr1 = 1.0f;
  float svr;
  {
    float v = V[lane] + V[64 + lane];
    #pragma unroll
    for (int o = 1; o < 64; o <<= 1) v += __shfl_xor(v, o, 64);
    svr = v;
  }
  const int jh = u >> 7;               // phase-C j-group 0..7 (wave-uniform)
  const int kc = u & 127;              // phase-C k ownership

  __syncthreads();   // steady LDS visible
  float hA = hbuf[64 * kh + lane];     // phase-A h half for this wave
  float* outb = out + (size_t)b * TT * TT;

  // ---------------- step loop ----------------
  #pragma unroll 1
  for (int step = 0; step < TT; ++step) {
    // ---- A: half-column zpart = Σ h_k · Wr[k][col] (+ptr@Wk | +bias) ----
    float zp0 = (kh == 0) ? (ptr0 * ra0 + ptr1 * ra1) : ra0;
    float zp1 = 0.0f;
    #pragma unroll
    for (int i = 0; i < 64; i += 2) {
      zp0 += rdlane(hA, i)     * wrreg[i];
      zp1 += rdlane(hA, i + 1) * wrreg[i + 1];
    }
    float zp = zp0 + zp1;
    if (u >= 512) sm.s.zpart[uu] = zp;
    __syncthreads();                   // (B1) zpart visible

    if (u < 512) {
      float z = zp + sm.s.zpart[uu];
      // quad exchange: all 4 gate preactivations to every lane of the quad
      float za = __shfl_xor(z, 1);
      float zb = __shfl_xor(z, 2);
      float zc = __shfl_xor(za, 2);
      float zi = (g == 0) ? z  : (g == 1) ? za : (g == 2) ? zb : zc;
      float zf = (g == 0) ? za : (g == 1) ? z  : (g == 2) ? zc : zb;
      float zg = (g == 0) ? zb : (g == 1) ? zc : (g == 2) ? z  : za;
      float zo = (g == 0) ? zc : (g == 1) ? zb : (g == 2) ? za : z;
      float ig = fast_sigmoid(zi);
      float fg = fast_sigmoid(zf);
      float gg = fast_tanh(zg);
      float og = fast_sigmoid(zo);
      c = fg * c + ig * gg;
      float hn = og * fast_tanh(c);
      if (g == 0) hbuf[m] = hn;
    }
    __syncthreads();                   // (B2) new h visible
    hA = hbuf[64 * kh + lane];
    float hC = hbuf[16 * jh + (lane & 15)];

    // ---- C: partial u_k over j in [16jh,16jh+16), k = kc; W2 from LDS ----
    {
      float cp0 = 0.0f, cp1 = 0.0f;
      #pragma unroll
      for (int i = 0; i < 16; i += 2) {
        cp0 += rdlane(hC, i)     * sm.s.w2[(16 * jh + i)     * HH + kc];
        cp1 += rdlane(hC, i + 1) * sm.s.w2[(16 * jh + i + 1) * HH + kc];
      }
      sm.s.part[jh * HH + kc] = cp0 + cp1;
    }
    __syncthreads();                   // (B3) C partials visible

    if (u < HH) {                      // U_k owners: sum 8 partials, exp2
      float s0 = sm.s.part[0 * HH + u] + sm.s.part[1 * HH + u];
      float s1 = sm.s.part[2 * HH + u] + sm.s.part[3 * HH + u];
      float s2 = sm.s.part[4 * HH + u] + sm.s.part[5 * HH + u];
      float s3 = sm.s.part[6 * HH + u] + sm.s.part[7 * HH + u];
      uvl[2 * u] = __builtin_amdgcn_exp2f(((s0 + s1) + (s2 + s3)) * C2);
    }
    __syncthreads();                   // (B3b) U visible

    // ---- D: wave w owns k=8w+j; lane l owns t∈{l,64+l,128+l,192+l} ----
    float acc0 = 0.0f, acc1 = 0.0f, acc2 = 0.0f, acc3 = 0.0f;
    {
      const float* uvp = &uvl[16 * w];   // wave-uniform -> broadcast reads
      #pragma unroll
      for (int ch = 0; ch < 2; ++ch) {
        float4 pa = *(const float4*)(uvp + 8 * ch);
        float4 pb = *(const float4*)(uvp + 8 * ch + 4);
        const int jb = 4 * ch;
        acc0 += pa.y * __builtin_amdgcn_rcpf(1.0f + Ereg[0*8+jb+0] * pa.x);
        acc1 += pa.y * __builtin_amdgcn_rcpf(1.0f + Ereg[1*8+jb+0] * pa.x);
        acc2 += pa.y * __builtin_amdgcn_rcpf(1.0f + Ereg[2*8+jb+0] * pa.x);
        acc3 += pa.y * __builtin_amdgcn_rcpf(1.0f + Ereg[3*8+jb+0] * pa.x);
        acc0 += pa.w * __builtin_amdgcn_rcpf(1.0f + Ereg[0*8+jb+1] * pa.z);
        acc1 += pa.w * __builtin_amdgcn_rcpf(1.0f + Ereg[1*8+jb+1] * pa.z);
        acc2 += pa.w * __builtin_amdgcn_rcpf(1.0f + Ereg[2*8+jb+1] * pa.z);
        acc3 += pa.w * __builtin_amdgcn_rcpf(1.0f + Ereg[3*8+jb+1] * pa.z);
        acc0 += pb.y * __builtin_amdgcn_rcpf(1.0f + Ereg[0*8+jb+2] * pb.x);
        acc1 += pb.y * __builtin_amdgcn_rcpf(1.0f + Ereg[1*8+jb+2] * pb.x);
        acc2 += pb.y * __builtin_amdgcn_rcpf(1.0f + Ereg[2*8+jb+2] * pb.x);
        acc3 += pb.y * __builtin_amdgcn_rcpf(1.0f + Ereg[3*8+jb+2] * pb.x);
        acc0 += pb.w * __builtin_amdgcn_rcpf(1.0f + Ereg[0*8+jb+3] * pb.z);
        acc1 += pb.w * __builtin_amdgcn_rcpf(1.0f + Ereg[1*8+jb+3] * pb.z);
        acc2 += pb.w * __builtin_amdgcn_rcpf(1.0f + Ereg[2*8+jb+3] * pb.z);
        acc3 += pb.w * __builtin_amdgcn_rcpf(1.0f + Ereg[3*8+jb+3] * pb.z);
      }
      sm.s.scp[w * 257 + 0 * 64 + lane] = acc0;
      sm.s.scp[w * 257 + 1 * 64 + lane] = acc1;
      sm.s.scp[w * 257 + 2 * 64 + lane] = acc2;
      sm.s.scp[w * 257 + 3 * 64 + lane] = acc3;
    }
    __syncthreads();                   // (B4) score partials visible

    // ---- scores, argmax, softmax-sum: threads 0..255 (t = u) ----
    float p = 0.0f;
    if (u < 256) {
      float s0 = 0.0f, s1 = 0.0f;
      #pragma unroll
      for (int q = 0; q < 16; q += 2) {
        s0 += sm.s.scp[q * 257 + u];
        s1 += sm.s.scp[(q + 1) * 257 + u];
      }
      float score = svr + s0 + s1;
      p = __builtin_amdgcn_exp2f((score - 12.0f) * L2E);  // fixed-shift numerator
      float bs = score; int bt = u;
      float wsv = p;
      #pragma unroll
      for (int o = 1; o < 64; o <<= 1) {
        float s2v = __shfl_xor(bs, o);
        int   t2v = __shfl_xor(bt, o);
        if (s2v > bs || (s2v == bs && t2v < bt)) { bs = s2v; bt = t2v; }
        wsv += __shfl_xor(wsv, o);
      }
      if (lane == 0) { amax_s[w] = bs; amax_t[w] = bt; ssum[w] = wsv; }
    }
    __syncthreads();                   // (B5) block partials visible

    float fbs = amax_s[0]; int fbt = amax_t[0];
    #pragma unroll
    for (int q = 1; q < 4; ++q) {
      float s2v = amax_s[q]; int t2v = amax_t[q];
      if (s2v > fbs || (s2v == fbs && t2v < fbt)) { fbs = s2v; fbt = t2v; }
    }
    float sumtot = (ssum[0] + ssum[1]) + (ssum[2] + ssum[3]);
    ptr0 = xloc[2 * fbt + 0];
    ptr1 = xloc[2 * fbt + 1];
    if (u < 256) outb[(size_t)step * TT + u] = p * __builtin_amdgcn_rcpf(sumtot);
  }
}

extern "C" void kernel_launch(void* const* d_in, const int* in_sizes, int n_in,
                              void* d_out, int out_size, void* d_ws, size_t ws_size,
                              hipStream_t stream) {
  (void)in_sizes; (void)n_in; (void)d_ws; (void)ws_size; (void)out_size;
  const float* x    = (const float*)d_in[0];
  const float* enc  = (const float*)d_in[1];
  const float* h0   = (const float*)d_in[2];
  const float* c0   = (const float*)d_in[3];
  const float* W1   = (const float*)d_in[4];
  const float* W2   = (const float*)d_in[5];
  const float* V    = (const float*)d_in[6];
  const float* Wk   = (const float*)d_in[7];
  const float* Wr   = (const float*)d_in[8];
  const float* bias = (const float*)d_in[9];
  float* out = (float*)d_out;

  decoder_kernel<<<64, 1024, 0, stream>>>(x, enc, h0, c0, W1, W2, V, Wk, Wr, bias, out);
}

// Round 6
// 948.047 us; speedup vs baseline: 1.5184x; 1.5184x over previous
//
#include <hip/hip_runtime.h>
#include <cstddef>

#define TT 256
#define HH 128
#define EST 132   // E row stride: lane-varying b128 reads hit every bank exactly
                  // 8 dwords/wave = balanced full-BW

__device__ __forceinline__ float rdlane(float v, int l) {
  return __int_as_float(__builtin_amdgcn_readlane(__float_as_int(v), l));
}
__device__ __forceinline__ float fast_sigmoid(float x) {
  const float L2E = 1.4426950408889634f;
  float y = __builtin_amdgcn_exp2f(-x * L2E);
  return __builtin_amdgcn_rcpf(1.0f + y);
}
__device__ __forceinline__ float fast_tanh(float x) {
  const float C2 = 2.8853900817779268f;   // 2*log2(e)
  float y = __builtin_amdgcn_exp2f(x * C2);
  return 1.0f - 2.0f * __builtin_amdgcn_rcpf(1.0f + y);
}

// One workgroup per batch element; 512 threads = 8 waves (2/SIMD).
// Wr as 4-col x 32-k register tiles (1.25 inst/MAC); W2 slice in regs;
// E=exp2(C2*enc_proj) in LDS; phase D 4t x 16k with amortized U readlanes.
__global__ __launch_bounds__(512, 2)
void decoder_kernel(const float* __restrict__ x,
                    const float* __restrict__ enc_output,
                    const float* __restrict__ h0,
                    const float* __restrict__ c0,
                    const float* __restrict__ W1,
                    const float* __restrict__ W2,
                    const float* __restrict__ V,
                    const float* __restrict__ Wk,
                    const float* __restrict__ Wr,
                    const float* __restrict__ bias,
                    float* __restrict__ out)
{
  __shared__ float E[TT * EST];      // 135168 B
  __shared__ float zpart[4 * 512];   // 8192 B : phase-A k-quarter partials
  __shared__ float part[8][64];      // 2048 B : phase-C partials
  __shared__ float scp[8 * 257];     // 8224 B : phase-D partials (padded)
  __shared__ float hbuf[HH];
  __shared__ float xloc[TT * 2];
  __shared__ float amax_s[4];
  __shared__ int   amax_t[4];
  __shared__ float ssum[4];

  const int u    = threadIdx.x;
  const int b    = blockIdx.x;
  const int lane = u & 63;
  const int w    = u >> 6;           // wave 0..7
  const float C2  = 2.8853900817779268f;
  const float L2E = 1.4426950408889634f;

  // ---------------- P0: enc_proj = enc_output[b] @ W1 -> E (raw) ----------------
  {
    const float* encb = enc_output + (size_t)b * TT * HH;
    const int tsub = u >> 4;
    const int ks   = (u & 15) * 8;
    for (int p = 0; p < 8; ++p) {
      const int tt = p * 32 + tsub;
      float4 a0 = {0.f, 0.f, 0.f, 0.f};
      float4 a1 = {0.f, 0.f, 0.f, 0.f};
      const float4* er4 = (const float4*)(encb + tt * HH);
      for (int j4 = 0; j4 < 32; ++j4) {
        const float4 ev = er4[j4];
        const float* w1p = W1 + (j4 * 4) * HH + ks;
        float4 wa, wb;
        wa = *(const float4*)(w1p + 0 * HH); wb = *(const float4*)(w1p + 0 * HH + 4);
        a0.x += ev.x * wa.x; a0.y += ev.x * wa.y; a0.z += ev.x * wa.z; a0.w += ev.x * wa.w;
        a1.x += ev.x * wb.x; a1.y += ev.x * wb.y; a1.z += ev.x * wb.z; a1.w += ev.x * wb.w;
        wa = *(const float4*)(w1p + 1 * HH); wb = *(const float4*)(w1p + 1 * HH + 4);
        a0.x += ev.y * wa.x; a0.y += ev.y * wa.y; a0.z += ev.y * wa.z; a0.w += ev.y * wa.w;
        a1.x += ev.y * wb.x; a1.y += ev.y * wb.y; a1.z += ev.y * wb.z; a1.w += ev.y * wb.w;
        wa = *(const float4*)(w1p + 2 * HH); wb = *(const float4*)(w1p + 2 * HH + 4);
        a0.x += ev.z * wa.x; a0.y += ev.z * wa.y; a0.z += ev.z * wa.z; a0.w += ev.z * wa.w;
        a1.x += ev.z * wb.x; a1.y += ev.z * wb.y; a1.z += ev.z * wb.z; a1.w += ev.z * wb.w;
        wa = *(const float4*)(w1p + 3 * HH); wb = *(const float4*)(w1p + 3 * HH + 4);
        a0.x += ev.w * wa.x; a0.y += ev.w * wa.y; a0.z += ev.w * wa.z; a0.w += ev.w * wa.w;
        a1.x += ev.w * wb.x; a1.y += ev.w * wb.y; a1.z += ev.w * wb.z; a1.w += ev.w * wb.w;
      }
      *(float4*)(&E[tt * EST + ks])     = a0;
      *(float4*)(&E[tt * EST + ks + 4]) = a1;
    }
  }
  xloc[u] = x[b * (TT * 2) + u];
  if (u < HH) hbuf[u] = h0[b * HH + u];

  // ---------------- persistent registers ----------------
  // Phase A: thread (kq = u>>7, cs = u&127) owns cols 4cs..4cs+3, k in [32kq,32kq+32)
  const int kq = u >> 7;
  const int cs = u & 127;
  float4 wr4[32];
  #pragma unroll
  for (int i = 0; i < 32; ++i)
    wr4[i] = *(const float4*)(Wr + (32 * kq + i) * 512 + 4 * cs);
  // Gate role: col = g*128 + m
  const int g = u & 3;
  const int m = u >> 2;
  const int col = g * HH + m;
  const float wk0 = Wk[col];
  const float wk1 = Wk[512 + col];
  const float bb  = bias[col];
  // Phase C (R4 mapping): wave w -> half=w&1, tq=w>>1; k=64*half+lane, j in [32tq,+32)
  const int halfC = w & 1;
  const int tqC   = w >> 1;
  float w2col[32];
  #pragma unroll
  for (int jj = 0; jj < 32; ++jj)
    w2col[jj] = W2[(32 * tqC + jj) * HH + 64 * halfC + lane];
  // Phase D: wave w owns k* range [16w,16w+16); per-lane kstar for U/v2
  const int kstar = 16 * w + (lane & 15);
  const int pD    = kstar >> 6;        // parity selecting part rows
  const int lD    = kstar & 63;
  const float v2r = -2.0f * V[kstar];
  float c = c0[b * HH + m];
  float ptr0 = 1.0f, ptr1 = 1.0f;
  float svr;
  {
    float v = V[lane] + V[64 + lane];
    #pragma unroll
    for (int o = 1; o < 64; o <<= 1) v += __shfl_xor(v, o, 64);
    svr = v;
  }

  __syncthreads();   // P0 + hbuf/xloc visible

  // ---------------- P1: E = exp2(C2 * enc_proj) in place ----------------
  {
    float* Er = &E[(u >> 1) * EST + 64 * (u & 1)];
    #pragma unroll
    for (int i = 0; i < 16; ++i) {
      float4 ev = *(const float4*)(Er + 4 * i);
      ev.x = __builtin_amdgcn_exp2f(ev.x * C2);
      ev.y = __builtin_amdgcn_exp2f(ev.y * C2);
      ev.z = __builtin_amdgcn_exp2f(ev.z * C2);
      ev.w = __builtin_amdgcn_exp2f(ev.w * C2);
      *(float4*)(Er + 4 * i) = ev;
    }
  }
  float hA = hbuf[32 * kq + (lane & 31)];        // phase-A k-slice h
  float hC = hbuf[32 * tqC + (lane & 31)];       // phase-C j-slice h
  __syncthreads();   // P1 done (E final); pre-loop h reads complete (race fix:
                     // first hbuf write is behind B1, which orders it after these)

  float* outb = out + (size_t)b * TT * TT;

  // ---------------- step loop ----------------
  #pragma unroll 1
  for (int step = 0; step < TT; ++step) {
    // ---- A: 4-col x 32-k slice: 1 readlane + 4 fmac per k ----
    {
      float4 zac = {0.f, 0.f, 0.f, 0.f};
      #pragma unroll
      for (int i = 0; i < 32; ++i) {
        float hi = rdlane(hA, i);
        zac.x += hi * wr4[i].x;
        zac.y += hi * wr4[i].y;
        zac.z += hi * wr4[i].z;
        zac.w += hi * wr4[i].w;
      }
      *(float4*)(&zpart[kq * 512 + 4 * cs]) = zac;
    }
    __syncthreads();                   // (B1) zpart visible

    // ---- gates: z = b + ptr@Wk + sum of 4 k-quarter partials ----
    {
      float z = bb + ptr0 * wk0 + ptr1 * wk1;
      z += (zpart[0 * 512 + col] + zpart[1 * 512 + col]) +
           (zpart[2 * 512 + col] + zpart[3 * 512 + col]);
      float za = __shfl_xor(z, 1);
      float zb = __shfl_xor(z, 2);
      float zc = __shfl_xor(za, 2);
      float zi = (g == 0) ? z  : (g == 1) ? za : (g == 2) ? zb : zc;
      float zf = (g == 0) ? za : (g == 1) ? z  : (g == 2) ? zc : zb;
      float zg = (g == 0) ? zb : (g == 1) ? zc : (g == 2) ? z  : za;
      float zo = (g == 0) ? zc : (g == 1) ? zb : (g == 2) ? za : z;
      float ig = fast_sigmoid(zi);
      float fg = fast_sigmoid(zf);
      float gg = fast_tanh(zg);
      float og = fast_sigmoid(zo);
      c = fg * c + ig * gg;
      float hn = og * fast_tanh(c);
      if (g == 0) hbuf[m] = hn;
    }
    __syncthreads();                   // (B2) new h visible
    hA = hbuf[32 * kq + (lane & 31)];
    hC = hbuf[32 * tqC + (lane & 31)];

    // ---- C: partial u_k; wave w: k=64*halfC+lane, j in [32tqC,+32); W2 regs ----
    {
      float cp0 = 0.0f, cp1 = 0.0f;
      #pragma unroll
      for (int jj = 0; jj < 32; jj += 2) {
        cp0 += rdlane(hC, jj)     * w2col[jj];
        cp1 += rdlane(hC, jj + 1) * w2col[jj + 1];
      }
      part[w][lane] = cp0 + cp1;
    }
    __syncthreads();                   // (B3) C partials visible

    // ---- U for this wave's k-range (redundant per-wave, no barrier) ----
    float Uk;
    {
      float usum = (part[pD][lD] + part[pD + 2][lD]) +
                   (part[pD + 4][lD] + part[pD + 6][lD]);
      Uk = __builtin_amdgcn_exp2f(usum * C2);
    }

    // ---- D: wave w, k in [16w,16w+16); lane owns t in {lane,64+,128+,192+} ----
    {
      float uL[16], vL[16];
      #pragma unroll
      for (int i = 0; i < 16; ++i) {
        uL[i] = rdlane(Uk, i);
        vL[i] = rdlane(v2r, i);
      }
      #pragma unroll
      for (int tt = 0; tt < 4; ++tt) {
        const float* Er = &E[(64 * tt + lane) * EST + 16 * w];
        float4 e0 = *(const float4*)(Er + 0);
        float4 e1 = *(const float4*)(Er + 4);
        float4 e2 = *(const float4*)(Er + 8);
        float4 e3 = *(const float4*)(Er + 12);
        float a0 = 0.0f, a1 = 0.0f;
        a0 += vL[ 0] * __builtin_amdgcn_rcpf(1.0f + e0.x * uL[ 0]);
        a1 += vL[ 1] * __builtin_amdgcn_rcpf(1.0f + e0.y * uL[ 1]);
        a0 += vL[ 2] * __builtin_amdgcn_rcpf(1.0f + e0.z * uL[ 2]);
        a1 += vL[ 3] * __builtin_amdgcn_rcpf(1.0f + e0.w * uL[ 3]);
        a0 += vL[ 4] * __builtin_amdgcn_rcpf(1.0f + e1.x * uL[ 4]);
        a1 += vL[ 5] * __builtin_amdgcn_rcpf(1.0f + e1.y * uL[ 5]);
        a0 += vL[ 6] * __builtin_amdgcn_rcpf(1.0f + e1.z * uL[ 6]);
        a1 += vL[ 7] * __builtin_amdgcn_rcpf(1.0f + e1.w * uL[ 7]);
        a0 += vL[ 8] * __builtin_amdgcn_rcpf(1.0f + e2.x * uL[ 8]);
        a1 += vL[ 9] * __builtin_amdgcn_rcpf(1.0f + e2.y * uL[ 9]);
        a0 += vL[10] * __builtin_amdgcn_rcpf(1.0f + e2.z * uL[10]);
        a1 += vL[11] * __builtin_amdgcn_rcpf(1.0f + e2.w * uL[11]);
        a0 += vL[12] * __builtin_amdgcn_rcpf(1.0f + e3.x * uL[12]);
        a1 += vL[13] * __builtin_amdgcn_rcpf(1.0f + e3.y * uL[13]);
        a0 += vL[14] * __builtin_amdgcn_rcpf(1.0f + e3.z * uL[14]);
        a1 += vL[15] * __builtin_amdgcn_rcpf(1.0f + e3.w * uL[15]);
        scp[w * 257 + 64 * tt + lane] = a0 + a1;
      }
    }
    __syncthreads();                   // (B4) score partials visible

    // ---- reduce, softmax, argmax: threads 0..255 (t = u) ----
    float p = 0.0f;
    if (u < 256) {
      float s0 = 0.0f, s1 = 0.0f;
      #pragma unroll
      for (int q = 0; q < 8; q += 2) {
        s0 += scp[q * 257 + u];
        s1 += scp[(q + 1) * 257 + u];
      }
      float score = svr + s0 + s1;
      p = __builtin_amdgcn_exp2f((score - 12.0f) * L2E);  // fixed-shift numerator
      float mx = score;
      float wsv = p;
      #pragma unroll
      for (int o = 1; o < 64; o <<= 1) {
        mx = fmaxf(mx, __shfl_xor(mx, o));
        wsv += __shfl_xor(wsv, o);
      }
      unsigned long long bal = __ballot(score == mx);
      int bt = 64 * w + (__ffsll(bal) - 1);   // first-max = lowest t in wave
      if (lane == 0) { amax_s[w] = mx; amax_t[w] = bt; ssum[w] = wsv; }
    }
    __syncthreads();                   // (B5) block partials visible

    float fbs = amax_s[0]; int fbt = amax_t[0];
    #pragma unroll
    for (int q = 1; q < 4; ++q) {
      float s2v = amax_s[q]; int t2v = amax_t[q];
      if (s2v > fbs || (s2v == fbs && t2v < fbt)) { fbs = s2v; fbt = t2v; }
    }
    float sumtot = (ssum[0] + ssum[1]) + (ssum[2] + ssum[3]);
    ptr0 = xloc[2 * fbt + 0];
    ptr1 = xloc[2 * fbt + 1];
    if (u < 256) outb[(size_t)step * TT + u] = p * __builtin_amdgcn_rcpf(sumtot);
  }
}

extern "C" void kernel_launch(void* const* d_in, const int* in_sizes, int n_in,
                              void* d_out, int out_size, void* d_ws, size_t ws_size,
                              hipStream_t stream) {
  (void)in_sizes; (void)n_in; (void)d_ws; (void)ws_size; (void)out_size;
  const float* x    = (const float*)d_in[0];
  const float* enc  = (const float*)d_in[1];
  const float* h0   = (const float*)d_in[2];
  const float* c0   = (const float*)d_in[3];
  const float* W1   = (const float*)d_in[4];
  const float* W2   = (const float*)d_in[5];
  const float* V    = (const float*)d_in[6];
  const float* Wk   = (const float*)d_in[7];
  const float* Wr   = (const float*)d_in[8];
  const float* bias = (const float*)d_in[9];
  float* out = (float*)d_out;

  decoder_kernel<<<64, 512, 0, stream>>>(x, enc, h0, c0, W1, W2, V, Wk, Wr, bias, out);
}

// Round 7
// 869.975 us; speedup vs baseline: 1.6546x; 1.0897x over previous
//
#include <hip/hip_runtime.h>
#include <cstddef>

#define TT 256
#define HH 128
#define EST 132   // E row stride: b128 reads land 8 dwords on every bank = balanced

__device__ __forceinline__ float rdlane(float v, int l) {
  return __int_as_float(__builtin_amdgcn_readlane(__float_as_int(v), l));
}
__device__ __forceinline__ float fast_sigmoid(float x) {
  const float L2E = 1.4426950408889634f;
  float y = __builtin_amdgcn_exp2f(-x * L2E);
  return __builtin_amdgcn_rcpf(1.0f + y);
}
__device__ __forceinline__ float fast_tanh(float x) {
  const float C2 = 2.8853900817779268f;   // 2*log2(e)
  float y = __builtin_amdgcn_exp2f(x * C2);
  return 1.0f - 2.0f * __builtin_amdgcn_rcpf(1.0f + y);
}

// One workgroup per batch element; 512 threads = 8 waves (2/SIMD).
// Restructured dataflow: h@Wr (Apre) overlaps phase D in one barrier window
// (VALU fmac + trans rcp co-issue); 4 barriers/step; pair-merged rcp in D.
__global__ __launch_bounds__(512, 2)
void decoder_kernel(const float* __restrict__ x,
                    const float* __restrict__ enc_output,
                    const float* __restrict__ h0,
                    const float* __restrict__ c0,
                    const float* __restrict__ W1,
                    const float* __restrict__ W2,
                    const float* __restrict__ V,
                    const float* __restrict__ Wk,
                    const float* __restrict__ Wr,
                    const float* __restrict__ bias,
                    float* __restrict__ out)
{
  __shared__ float E[TT * EST];      // 135168 B : exp2(C2 * enc_proj)
  __shared__ float zpart[4 * 512];   // 8192 B   : h@Wr k-quarter partials
  __shared__ float part[8][64];      // 2048 B   : phase-C partials
  __shared__ float scp[8 * 257];     // 8224 B   : phase-D partials (padded)
  __shared__ float hbuf[HH];
  __shared__ float xloc[TT * 2];
  __shared__ float amax_s[4];
  __shared__ int   amax_t[4];
  __shared__ float ssum[4];

  const int u    = threadIdx.x;
  const int b    = blockIdx.x;
  const int lane = u & 63;
  const int w    = u >> 6;           // wave 0..7
  const float C2  = 2.8853900817779268f;
  const float L2E = 1.4426950408889634f;

  // ---------------- P0: enc_proj = enc_output[b] @ W1 -> E (raw) ----------------
  {
    const float* encb = enc_output + (size_t)b * TT * HH;
    const int tsub = u >> 4;
    const int ks   = (u & 15) * 8;
    for (int p = 0; p < 8; ++p) {
      const int tt = p * 32 + tsub;
      float4 a0 = {0.f, 0.f, 0.f, 0.f};
      float4 a1 = {0.f, 0.f, 0.f, 0.f};
      const float4* er4 = (const float4*)(encb + tt * HH);
      for (int j4 = 0; j4 < 32; ++j4) {
        const float4 ev = er4[j4];
        const float* w1p = W1 + (j4 * 4) * HH + ks;
        float4 wa, wb;
        wa = *(const float4*)(w1p + 0 * HH); wb = *(const float4*)(w1p + 0 * HH + 4);
        a0.x += ev.x * wa.x; a0.y += ev.x * wa.y; a0.z += ev.x * wa.z; a0.w += ev.x * wa.w;
        a1.x += ev.x * wb.x; a1.y += ev.x * wb.y; a1.z += ev.x * wb.z; a1.w += ev.x * wb.w;
        wa = *(const float4*)(w1p + 1 * HH); wb = *(const float4*)(w1p + 1 * HH + 4);
        a0.x += ev.y * wa.x; a0.y += ev.y * wa.y; a0.z += ev.y * wa.z; a0.w += ev.y * wa.w;
        a1.x += ev.y * wb.x; a1.y += ev.y * wb.y; a1.z += ev.y * wb.z; a1.w += ev.y * wb.w;
        wa = *(const float4*)(w1p + 2 * HH); wb = *(const float4*)(w1p + 2 * HH + 4);
        a0.x += ev.z * wa.x; a0.y += ev.z * wa.y; a0.z += ev.z * wa.z; a0.w += ev.z * wa.w;
        a1.x += ev.z * wb.x; a1.y += ev.z * wb.y; a1.z += ev.z * wb.z; a1.w += ev.z * wb.w;
        wa = *(const float4*)(w1p + 3 * HH); wb = *(const float4*)(w1p + 3 * HH + 4);
        a0.x += ev.w * wa.x; a0.y += ev.w * wa.y; a0.z += ev.w * wa.z; a0.w += ev.w * wa.w;
        a1.x += ev.w * wb.x; a1.y += ev.w * wb.y; a1.z += ev.w * wb.z; a1.w += ev.w * wb.w;
      }
      *(float4*)(&E[tt * EST + ks])     = a0;
      *(float4*)(&E[tt * EST + ks + 4]) = a1;
    }
  }
  xloc[u] = x[b * (TT * 2) + u];
  if (u < HH) hbuf[u] = h0[b * HH + u];

  // ---------------- persistent registers ----------------
  // Apre: thread (kq = u>>7, cs = u&127) owns cols 4cs..4cs+3, k in [32kq,+32)
  const int kq = u >> 7;
  const int cs = u & 127;
  float4 wr4[32];
  #pragma unroll
  for (int i = 0; i < 32; ++i)
    wr4[i] = *(const float4*)(Wr + (32 * kq + i) * 512 + 4 * cs);
  // Gate role: col = g*128 + m
  const int g = u & 3;
  const int m = u >> 2;
  const int col = g * HH + m;
  const float wk0 = Wk[col];
  const float wk1 = Wk[512 + col];
  const float bb  = bias[col];
  // Phase C: wave w -> halfC=w&1, tqC=w>>1; k=64*halfC+lane, j in [32tqC,+32)
  const int halfC = w & 1;
  const int tqC   = w >> 1;
  float w2col[32];
  #pragma unroll
  for (int jj = 0; jj < 32; ++jj)
    w2col[jj] = W2[(32 * tqC + jj) * HH + 64 * halfC + lane];
  // Phase D: wave w owns k in [16w,16w+16)
  const int kstar = 16 * w + (lane & 15);
  const int pD    = kstar >> 6;
  const int lD    = kstar & 63;
  const float v2r = -2.0f * V[kstar];
  float c = c0[b * HH + m];
  float ptr0 = 1.0f, ptr1 = 1.0f;
  float svr;
  {
    float v = V[lane] + V[64 + lane];
    #pragma unroll
    for (int o = 1; o < 64; o <<= 1) v += __shfl_xor(v, o, 64);
    svr = v;
  }

  __syncthreads();   // P0 + hbuf/xloc visible

  // ---------------- P1: E = exp2(C2 * enc_proj) in place (own chunks) ----------
  {
    float* Er = &E[(u >> 1) * EST + 64 * (u & 1)];
    #pragma unroll
    for (int i = 0; i < 16; ++i) {
      float4 ev = *(const float4*)(Er + 4 * i);
      ev.x = __builtin_amdgcn_exp2f(ev.x * C2);
      ev.y = __builtin_amdgcn_exp2f(ev.y * C2);
      ev.z = __builtin_amdgcn_exp2f(ev.z * C2);
      ev.w = __builtin_amdgcn_exp2f(ev.w * C2);
      *(float4*)(Er + 4 * i) = ev;
    }
  }
  // loop-invariant phase-D v-broadcast
  float vL[16];
  #pragma unroll
  for (int i = 0; i < 16; ++i) vL[i] = rdlane(v2r, i);

  float hA = hbuf[32 * kq + (lane & 31)];
  float hC = hbuf[32 * tqC + (lane & 31)];
  // prologue Apre: zpart = h0 @ Wr
  {
    float4 zac = {0.f, 0.f, 0.f, 0.f};
    #pragma unroll
    for (int i = 0; i < 32; ++i) {
      float hi = rdlane(hA, i);
      zac.x += hi * wr4[i].x;
      zac.y += hi * wr4[i].y;
      zac.z += hi * wr4[i].z;
      zac.w += hi * wr4[i].w;
    }
    *(float4*)(&zpart[kq * 512 + 4 * cs]) = zac;
  }
  __syncthreads();   // E final + zpart(h0) visible; h0 reads ordered before (a)'s
                     // hbuf write (race discipline from R3 post-mortem)

  float* outb = out + (size_t)b * TT * TT;

  // ---------------- step loop (4 barriers) ----------------
  #pragma unroll 1
  for (int step = 0; step < TT; ++step) {
    // ---- (a) gates: z = b + ptr@Wk + Σ zpart(h_s@Wr) ----
    {
      float z = bb + ptr0 * wk0 + ptr1 * wk1;
      z += (zpart[0 * 512 + col] + zpart[1 * 512 + col]) +
           (zpart[2 * 512 + col] + zpart[3 * 512 + col]);
      float za = __shfl_xor(z, 1);
      float zb = __shfl_xor(z, 2);
      float zc = __shfl_xor(za, 2);
      float zi = (g == 0) ? z  : (g == 1) ? za : (g == 2) ? zb : zc;
      float zf = (g == 0) ? za : (g == 1) ? z  : (g == 2) ? zc : zb;
      float zg = (g == 0) ? zb : (g == 1) ? zc : (g == 2) ? z  : za;
      float zo = (g == 0) ? zc : (g == 1) ? zb : (g == 2) ? za : z;
      float ig = fast_sigmoid(zi);
      float fg = fast_sigmoid(zf);
      float gg = fast_tanh(zg);
      float og = fast_sigmoid(zo);
      c = fg * c + ig * gg;
      float hn = og * fast_tanh(c);
      if (g == 0) hbuf[m] = hn;      // h_{s+1}
    }
    __syncthreads();                 // (W1) new h visible
    hA = hbuf[32 * kq + (lane & 31)];
    hC = hbuf[32 * tqC + (lane & 31)];

    // ---- (b) C: partial u_k = h@W2; wave w: k=64*halfC+lane, j in [32tqC,+32) ----
    {
      float cp0 = 0.0f, cp1 = 0.0f;
      #pragma unroll
      for (int jj = 0; jj < 32; jj += 2) {
        cp0 += rdlane(hC, jj)     * w2col[jj];
        cp1 += rdlane(hC, jj + 1) * w2col[jj + 1];
      }
      part[w][lane] = cp0 + cp1;
    }
    __syncthreads();                 // (W2) C partials visible

    // ---- (c) U + D (pair-merged rcp) + Apre(h_{s+1}@Wr) in ONE window ----
    float Uk;
    {
      float usum = (part[pD][lD] + part[pD + 2][lD]) +
                   (part[pD + 4][lD] + part[pD + 6][lD]);
      Uk = __builtin_amdgcn_exp2f(usum * C2);
    }
    {
      float uL[16];
      #pragma unroll
      for (int i = 0; i < 16; ++i) uL[i] = rdlane(Uk, i);
      #pragma unroll
      for (int tt = 0; tt < 4; ++tt) {
        const float* Er = &E[(64 * tt + lane) * EST + 16 * w];
        float4 e0 = *(const float4*)(Er + 0);
        float4 e1 = *(const float4*)(Er + 4);
        float4 e2 = *(const float4*)(Er + 8);
        float4 e3 = *(const float4*)(Er + 12);
        float a0 = 0.0f, a1 = 0.0f;
        float t0, t1, n;
        // pairs (k, k+1): v0/t0 + v1/t1 = (v0*t1 + v1*t0) * rcp(t0*t1)
        t0 = fmaf(e0.x, uL[ 0], 1.0f); t1 = fmaf(e0.y, uL[ 1], 1.0f);
        n  = fmaf(vL[ 1], t0, vL[ 0] * t1);
        a0 = fmaf(n, __builtin_amdgcn_rcpf(t0 * t1), a0);
        t0 = fmaf(e0.z, uL[ 2], 1.0f); t1 = fmaf(e0.w, uL[ 3], 1.0f);
        n  = fmaf(vL[ 3], t0, vL[ 2] * t1);
        a1 = fmaf(n, __builtin_amdgcn_rcpf(t0 * t1), a1);
        t0 = fmaf(e1.x, uL[ 4], 1.0f); t1 = fmaf(e1.y, uL[ 5], 1.0f);
        n  = fmaf(vL[ 5], t0, vL[ 4] * t1);
        a0 = fmaf(n, __builtin_amdgcn_rcpf(t0 * t1), a0);
        t0 = fmaf(e1.z, uL[ 6], 1.0f); t1 = fmaf(e1.w, uL[ 7], 1.0f);
        n  = fmaf(vL[ 7], t0, vL[ 6] * t1);
        a1 = fmaf(n, __builtin_amdgcn_rcpf(t0 * t1), a1);
        t0 = fmaf(e2.x, uL[ 8], 1.0f); t1 = fmaf(e2.y, uL[ 9], 1.0f);
        n  = fmaf(vL[ 9], t0, vL[ 8] * t1);
        a0 = fmaf(n, __builtin_amdgcn_rcpf(t0 * t1), a0);
        t0 = fmaf(e2.z, uL[10], 1.0f); t1 = fmaf(e2.w, uL[11], 1.0f);
        n  = fmaf(vL[11], t0, vL[10] * t1);
        a1 = fmaf(n, __builtin_amdgcn_rcpf(t0 * t1), a1);
        t0 = fmaf(e3.x, uL[12], 1.0f); t1 = fmaf(e3.y, uL[13], 1.0f);
        n  = fmaf(vL[13], t0, vL[12] * t1);
        a0 = fmaf(n, __builtin_amdgcn_rcpf(t0 * t1), a0);
        t0 = fmaf(e3.z, uL[14], 1.0f); t1 = fmaf(e3.w, uL[15], 1.0f);
        n  = fmaf(vL[15], t0, vL[14] * t1);
        a1 = fmaf(n, __builtin_amdgcn_rcpf(t0 * t1), a1);
        scp[w * 257 + 64 * tt + lane] = a0 + a1;
      }
    }
    {   // Apre: zpart = h_{s+1} @ Wr — fmac-heavy, co-issues with D's rcp tail
      float4 zac = {0.f, 0.f, 0.f, 0.f};
      #pragma unroll
      for (int i = 0; i < 32; ++i) {
        float hi = rdlane(hA, i);
        zac.x += hi * wr4[i].x;
        zac.y += hi * wr4[i].y;
        zac.z += hi * wr4[i].z;
        zac.w += hi * wr4[i].w;
      }
      *(float4*)(&zpart[kq * 512 + 4 * cs]) = zac;
    }
    __syncthreads();                 // (W3) scp + zpart visible

    // ---- (d) reduce scores, softmax numerator, argmax: threads 0..255 ----
    float p = 0.0f;
    if (u < 256) {
      float s0 = 0.0f, s1 = 0.0f;
      #pragma unroll
      for (int q = 0; q < 8; q += 2) {
        s0 += scp[q * 257 + u];
        s1 += scp[(q + 1) * 257 + u];
      }
      float score = svr + s0 + s1;
      p = __builtin_amdgcn_exp2f((score - 12.0f) * L2E);  // fixed-shift numerator
      float mx = score;
      float wsv = p;
      #pragma unroll
      for (int o = 1; o < 64; o <<= 1) {
        mx = fmaxf(mx, __shfl_xor(mx, o));
        wsv += __shfl_xor(wsv, o);
      }
      unsigned long long bal = __ballot(score == mx);
      int bt = 64 * w + (__ffsll(bal) - 1);   // first-max in wave
      if (lane == 0) { amax_s[w] = mx; amax_t[w] = bt; ssum[w] = wsv; }
    }
    __syncthreads();                 // (W4) block partials visible

    // ---- (e) finalize: ptr for next step, write probs row ----
    float fbs = amax_s[0]; int fbt = amax_t[0];
    #pragma unroll
    for (int q = 1; q < 4; ++q) {
      float s2v = amax_s[q]; int t2v = amax_t[q];
      if (s2v > fbs || (s2v == fbs && t2v < fbt)) { fbs = s2v; fbt = t2v; }
    }
    float sumtot = (ssum[0] + ssum[1]) + (ssum[2] + ssum[3]);
    ptr0 = xloc[2 * fbt + 0];
    ptr1 = xloc[2 * fbt + 1];
    if (u < 256) outb[(size_t)step * TT + u] = p * __builtin_amdgcn_rcpf(sumtot);
  }
}

extern "C" void kernel_launch(void* const* d_in, const int* in_sizes, int n_in,
                              void* d_out, int out_size, void* d_ws, size_t ws_size,
                              hipStream_t stream) {
  (void)in_sizes; (void)n_in; (void)d_ws; (void)ws_size; (void)out_size;
  const float* x    = (const float*)d_in[0];
  const float* enc  = (const float*)d_in[1];
  const float* h0   = (const float*)d_in[2];
  const float* c0   = (const float*)d_in[3];
  const float* W1   = (const float*)d_in[4];
  const float* W2   = (const float*)d_in[5];
  const float* V    = (const float*)d_in[6];
  const float* Wk   = (const float*)d_in[7];
  const float* Wr   = (const float*)d_in[8];
  const float* bias = (const float*)d_in[9];
  float* out = (float*)d_out;

  decoder_kernel<<<64, 512, 0, stream>>>(x, enc, h0, c0, W1, W2, V, Wk, Wr, bias, out);
}

// Round 8
// 841.511 us; speedup vs baseline: 1.7106x; 1.0338x over previous
//
#include <hip/hip_runtime.h>
#include <cstddef>

#define TT 256
#define HH 128
#define EST 132   // E row stride: b128 reads land 8 dwords on every bank = balanced

__device__ __forceinline__ float rdlane(float v, int l) {
  return __int_as_float(__builtin_amdgcn_readlane(__float_as_int(v), l));
}
__device__ __forceinline__ float fast_sigmoid(float x) {
  const float L2E = 1.4426950408889634f;
  float y = __builtin_amdgcn_exp2f(-x * L2E);
  return __builtin_amdgcn_rcpf(1.0f + y);
}
__device__ __forceinline__ float fast_tanh(float x) {
  const float C2 = 2.8853900817779268f;   // 2*log2(e)
  float y = __builtin_amdgcn_exp2f(x * C2);
  return 1.0f - 2.0f * __builtin_amdgcn_rcpf(1.0f + y);
}

// One workgroup per batch element; 512 threads = 8 waves (2/SIMD).
// 3 barriers/step: R(reduce+gates) -> W1 -> S(C+Apre) -> W2 -> T(U+D) -> W3.
// Reduce is wave-redundant on waves 0-3 (no cross-wave argmax barrier);
// gates are 1-thread-per-unit (no quad-exchange shfl chain).
__global__ __launch_bounds__(512, 2)
void decoder_kernel(const float* __restrict__ x,
                    const float* __restrict__ enc_output,
                    const float* __restrict__ h0,
                    const float* __restrict__ c0,
                    const float* __restrict__ W1,
                    const float* __restrict__ W2,
                    const float* __restrict__ V,
                    const float* __restrict__ Wk,
                    const float* __restrict__ Wr,
                    const float* __restrict__ bias,
                    float* __restrict__ out)
{
  __shared__ float E[TT * EST];      // 135168 B : exp2(C2 * enc_proj)
  __shared__ float zpart[4 * 512];   // 8192 B   : h@Wr k-quarter partials
  __shared__ float part[8][64];      // 2048 B   : phase-C partials
  __shared__ float scp[8 * 257];     // 8224 B   : phase-D partials (padded)
  __shared__ float hbuf[HH];
  __shared__ float xloc[TT * 2];

  const int u    = threadIdx.x;
  const int b    = blockIdx.x;
  const int lane = u & 63;
  const int w    = u >> 6;           // wave 0..7
  const float C2  = 2.8853900817779268f;
  const float L2E = 1.4426950408889634f;

  // ---------------- P0: enc_proj = enc_output[b] @ W1 -> E (raw) ----------------
  {
    const float* encb = enc_output + (size_t)b * TT * HH;
    const int tsub = u >> 4;
    const int ks   = (u & 15) * 8;
    for (int p = 0; p < 8; ++p) {
      const int tt = p * 32 + tsub;
      float4 a0 = {0.f, 0.f, 0.f, 0.f};
      float4 a1 = {0.f, 0.f, 0.f, 0.f};
      const float4* er4 = (const float4*)(encb + tt * HH);
      for (int j4 = 0; j4 < 32; ++j4) {
        const float4 ev = er4[j4];
        const float* w1p = W1 + (j4 * 4) * HH + ks;
        float4 wa, wb;
        wa = *(const float4*)(w1p + 0 * HH); wb = *(const float4*)(w1p + 0 * HH + 4);
        a0.x += ev.x * wa.x; a0.y += ev.x * wa.y; a0.z += ev.x * wa.z; a0.w += ev.x * wa.w;
        a1.x += ev.x * wb.x; a1.y += ev.x * wb.y; a1.z += ev.x * wb.z; a1.w += ev.x * wb.w;
        wa = *(const float4*)(w1p + 1 * HH); wb = *(const float4*)(w1p + 1 * HH + 4);
        a0.x += ev.y * wa.x; a0.y += ev.y * wa.y; a0.z += ev.y * wa.z; a0.w += ev.y * wa.w;
        a1.x += ev.y * wb.x; a1.y += ev.y * wb.y; a1.z += ev.y * wb.z; a1.w += ev.y * wb.w;
        wa = *(const float4*)(w1p + 2 * HH); wb = *(const float4*)(w1p + 2 * HH + 4);
        a0.x += ev.z * wa.x; a0.y += ev.z * wa.y; a0.z += ev.z * wa.z; a0.w += ev.z * wa.w;
        a1.x += ev.z * wb.x; a1.y += ev.z * wb.y; a1.z += ev.z * wb.z; a1.w += ev.z * wb.w;
        wa = *(const float4*)(w1p + 3 * HH); wb = *(const float4*)(w1p + 3 * HH + 4);
        a0.x += ev.w * wa.x; a0.y += ev.w * wa.y; a0.z += ev.w * wa.z; a0.w += ev.w * wa.w;
        a1.x += ev.w * wb.x; a1.y += ev.w * wb.y; a1.z += ev.w * wb.z; a1.w += ev.w * wb.w;
      }
      *(float4*)(&E[tt * EST + ks])     = a0;
      *(float4*)(&E[tt * EST + ks + 4]) = a1;
    }
  }
  xloc[u] = x[b * (TT * 2) + u];

  // ---------------- persistent registers ----------------
  // Apre: thread (kq = u>>7, cs = u&127) owns cols 4cs..4cs+3, k in [32kq,+32)
  const int kq = u >> 7;
  const int cs = u & 127;
  float4 wr4[32];
  #pragma unroll
  for (int i = 0; i < 32; ++i)
    wr4[i] = *(const float4*)(Wr + (32 * kq + i) * 512 + 4 * cs);
  // Gates: thread u<128 owns unit m=u, all 4 gates.
  const int m = u & 127;
  float wkA[4], wkB[4], bbg[4];
  #pragma unroll
  for (int gg = 0; gg < 4; ++gg) {
    wkA[gg] = Wk[gg * HH + m];
    wkB[gg] = Wk[512 + gg * HH + m];
    bbg[gg] = bias[gg * HH + m];
  }
  float c = c0[b * HH + m];          // valid for u<128 (others unused)
  // Phase C: wave w -> halfC=w&1, tqC=w>>1; k=64*halfC+lane, j in [32tqC,+32)
  const int halfC = w & 1;
  const int tqC   = w >> 1;
  float w2col[32];
  #pragma unroll
  for (int jj = 0; jj < 32; ++jj)
    w2col[jj] = W2[(32 * tqC + jj) * HH + 64 * halfC + lane];
  // Phase D: wave w owns k in [16w,16w+16)
  const int kstar = 16 * w + (lane & 15);
  const int pD    = kstar >> 6;
  const int lD    = kstar & 63;
  const float v2r = -2.0f * V[kstar];
  float ptr0 = 1.0f, ptr1 = 1.0f;
  float svr;
  {
    float v = V[lane] + V[64 + lane];
    #pragma unroll
    for (int o = 1; o < 64; o <<= 1) v += __shfl_xor(v, o, 64);
    svr = v;
  }

  __syncthreads();   // P0 staging + xloc visible

  // ---------------- P1: E = exp2(C2 * enc_proj) in place (own chunks) ----------
  {
    float* Er = &E[(u >> 1) * EST + 64 * (u & 1)];
    #pragma unroll
    for (int i = 0; i < 16; ++i) {
      float4 ev = *(const float4*)(Er + 4 * i);
      ev.x = __builtin_amdgcn_exp2f(ev.x * C2);
      ev.y = __builtin_amdgcn_exp2f(ev.y * C2);
      ev.z = __builtin_amdgcn_exp2f(ev.z * C2);
      ev.w = __builtin_amdgcn_exp2f(ev.w * C2);
      *(float4*)(Er + 4 * i) = ev;
    }
  }
  // loop-invariant phase-D v-broadcast
  float vL[16];
  #pragma unroll
  for (int i = 0; i < 16; ++i) vL[i] = rdlane(v2r, i);
  // prologue Apre: zpart = h0 @ Wr (h0 straight from global; hbuf not used for h0)
  {
    float hA0 = h0[(size_t)b * HH + 32 * kq + (lane & 31)];
    float4 zac = {0.f, 0.f, 0.f, 0.f};
    #pragma unroll
    for (int i = 0; i < 32; ++i) {
      float hi = rdlane(hA0, i);
      zac.x += hi * wr4[i].x;
      zac.y += hi * wr4[i].y;
      zac.z += hi * wr4[i].z;
      zac.w += hi * wr4[i].w;
    }
    *(float4*)(&zpart[kq * 512 + 4 * cs]) = zac;
  }
  __syncthreads();   // E final + zpart(h0) visible

  float* outb = out + (size_t)b * TT * TT;

  // ---------------- step loop: 3 barriers ----------------
  #pragma unroll 1
  for (int step = 0; step < TT; ++step) {
    // ==== R window: reduce scores(step-1) + ptr + gates -> h_step ====
    if (step > 0 && w < 4) {
      float s0 = 0.f, s1 = 0.f, s2 = 0.f, s3 = 0.f;
      #pragma unroll
      for (int q = 0; q < 8; ++q) {
        s0 += scp[q * 257 + 0 * 64 + lane];
        s1 += scp[q * 257 + 1 * 64 + lane];
        s2 += scp[q * 257 + 2 * 64 + lane];
        s3 += scp[q * 257 + 3 * 64 + lane];
      }
      s0 += svr; s1 += svr; s2 += svr; s3 += svr;
      // fixed-shift softmax numerators (|score| <= ~10.5; shift-invariant)
      float p0 = __builtin_amdgcn_exp2f((s0 - 12.0f) * L2E);
      float p1 = __builtin_amdgcn_exp2f((s1 - 12.0f) * L2E);
      float p2 = __builtin_amdgcn_exp2f((s2 - 12.0f) * L2E);
      float p3 = __builtin_amdgcn_exp2f((s3 - 12.0f) * L2E);
      float m4 = fmaxf(fmaxf(s0, s1), fmaxf(s2, s3));
      int ttl = (s0 == m4) ? 0 : (s1 == m4) ? 1 : (s2 == m4) ? 2 : 3;
      float ws4 = (p0 + p1) + (p2 + p3);
      float mx = m4;
      #pragma unroll
      for (int o = 1; o < 64; o <<= 1) {
        mx  = fmaxf(mx, __shfl_xor(mx, o));
        ws4 += __shfl_xor(ws4, o);
      }
      unsigned long long bal = __ballot(m4 == mx);
      int ls  = __ffsll((unsigned long long)bal) - 1;
      int tts = __builtin_amdgcn_readlane(ttl, ls);
      int fbt = 64 * tts + ls;
      ptr0 = xloc[2 * fbt + 0];
      ptr1 = xloc[2 * fbt + 1];
      float pw = (w == 0) ? p0 : (w == 1) ? p1 : (w == 2) ? p2 : p3;
      outb[(size_t)(step - 1) * TT + 64 * w + lane] = pw * __builtin_amdgcn_rcpf(ws4);
    }
    if (u < HH) {   // gates: unit m, all 4 gates in-thread (no shfl exchange)
      float z0 = bbg[0] + ptr0 * wkA[0] + ptr1 * wkB[0];
      float z1 = bbg[1] + ptr0 * wkA[1] + ptr1 * wkB[1];
      float z2 = bbg[2] + ptr0 * wkA[2] + ptr1 * wkB[2];
      float z3 = bbg[3] + ptr0 * wkA[3] + ptr1 * wkB[3];
      #pragma unroll
      for (int q = 0; q < 4; ++q) {
        z0 += zpart[q * 512 + 0 * HH + m];
        z1 += zpart[q * 512 + 1 * HH + m];
        z2 += zpart[q * 512 + 2 * HH + m];
        z3 += zpart[q * 512 + 3 * HH + m];
      }
      float ig = fast_sigmoid(z0);
      float fg = fast_sigmoid(z1);
      float gg = fast_tanh(z2);
      float og = fast_sigmoid(z3);
      c = fg * c + ig * gg;
      hbuf[m] = og * fast_tanh(c);
    }
    __syncthreads();                 // (W1) h_step visible

    // ==== S window: C (u_k partials) + Apre (h_step @ Wr) ====
    float hC = hbuf[32 * tqC + (lane & 31)];
    float hA = hbuf[32 * kq  + (lane & 31)];
    {
      float cp0 = 0.0f, cp1 = 0.0f;
      #pragma unroll
      for (int jj = 0; jj < 32; jj += 2) {
        cp0 += rdlane(hC, jj)     * w2col[jj];
        cp1 += rdlane(hC, jj + 1) * w2col[jj + 1];
      }
      part[w][lane] = cp0 + cp1;
    }
    {
      float4 zac = {0.f, 0.f, 0.f, 0.f};
      #pragma unroll
      for (int i = 0; i < 32; ++i) {
        float hi = rdlane(hA, i);
        zac.x += hi * wr4[i].x;
        zac.y += hi * wr4[i].y;
        zac.z += hi * wr4[i].z;
        zac.w += hi * wr4[i].w;
      }
      *(float4*)(&zpart[kq * 512 + 4 * cs]) = zac;
    }
    __syncthreads();                 // (W2) part + zpart visible

    // ==== T window: U + D (pair-merged rcp) -> scp ====
    float Uk;
    {
      float usum = (part[pD][lD] + part[pD + 2][lD]) +
                   (part[pD + 4][lD] + part[pD + 6][lD]);
      Uk = __builtin_amdgcn_exp2f(usum * C2);
    }
    {
      float uL[16];
      #pragma unroll
      for (int i = 0; i < 16; ++i) uL[i] = rdlane(Uk, i);
      #pragma unroll
      for (int tt = 0; tt < 4; ++tt) {
        const float* Er = &E[(64 * tt + lane) * EST + 16 * w];
        float4 e0 = *(const float4*)(Er + 0);
        float4 e1 = *(const float4*)(Er + 4);
        float4 e2 = *(const float4*)(Er + 8);
        float4 e3 = *(const float4*)(Er + 12);
        float a0 = 0.0f, a1 = 0.0f;
        float t0, t1, n;
        t0 = fmaf(e0.x, uL[ 0], 1.0f); t1 = fmaf(e0.y, uL[ 1], 1.0f);
        n  = fmaf(vL[ 1], t0, vL[ 0] * t1);
        a0 = fmaf(n, __builtin_amdgcn_rcpf(t0 * t1), a0);
        t0 = fmaf(e0.z, uL[ 2], 1.0f); t1 = fmaf(e0.w, uL[ 3], 1.0f);
        n  = fmaf(vL[ 3], t0, vL[ 2] * t1);
        a1 = fmaf(n, __builtin_amdgcn_rcpf(t0 * t1), a1);
        t0 = fmaf(e1.x, uL[ 4], 1.0f); t1 = fmaf(e1.y, uL[ 5], 1.0f);
        n  = fmaf(vL[ 5], t0, vL[ 4] * t1);
        a0 = fmaf(n, __builtin_amdgcn_rcpf(t0 * t1), a0);
        t0 = fmaf(e1.z, uL[ 6], 1.0f); t1 = fmaf(e1.w, uL[ 7], 1.0f);
        n  = fmaf(vL[ 7], t0, vL[ 6] * t1);
        a1 = fmaf(n, __builtin_amdgcn_rcpf(t0 * t1), a1);
        t0 = fmaf(e2.x, uL[ 8], 1.0f); t1 = fmaf(e2.y, uL[ 9], 1.0f);
        n  = fmaf(vL[ 9], t0, vL[ 8] * t1);
        a0 = fmaf(n, __builtin_amdgcn_rcpf(t0 * t1), a0);
        t0 = fmaf(e2.z, uL[10], 1.0f); t1 = fmaf(e2.w, uL[11], 1.0f);
        n  = fmaf(vL[11], t0, vL[10] * t1);
        a1 = fmaf(n, __builtin_amdgcn_rcpf(t0 * t1), a1);
        t0 = fmaf(e3.x, uL[12], 1.0f); t1 = fmaf(e3.y, uL[13], 1.0f);
        n  = fmaf(vL[13], t0, vL[12] * t1);
        a0 = fmaf(n, __builtin_amdgcn_rcpf(t0 * t1), a0);
        t0 = fmaf(e3.z, uL[14], 1.0f); t1 = fmaf(e3.w, uL[15], 1.0f);
        n  = fmaf(vL[15], t0, vL[14] * t1);
        a1 = fmaf(n, __builtin_amdgcn_rcpf(t0 * t1), a1);
        scp[w * 257 + 64 * tt + lane] = a0 + a1;
      }
    }
    __syncthreads();                 // (W3) scp visible
  }

  // ---------------- peel: reduce + store final row (step 255) ----------------
  if (w < 4) {
    float s0 = 0.f, s1 = 0.f, s2 = 0.f, s3 = 0.f;
    #pragma unroll
    for (int q = 0; q < 8; ++q) {
      s0 += scp[q * 257 + 0 * 64 + lane];
      s1 += scp[q * 257 + 1 * 64 + lane];
      s2 += scp[q * 257 + 2 * 64 + lane];
      s3 += scp[q * 257 + 3 * 64 + lane];
    }
    s0 += svr; s1 += svr; s2 += svr; s3 += svr;
    float p0 = __builtin_amdgcn_exp2f((s0 - 12.0f) * L2E);
    float p1 = __builtin_amdgcn_exp2f((s1 - 12.0f) * L2E);
    float p2 = __builtin_amdgcn_exp2f((s2 - 12.0f) * L2E);
    float p3 = __builtin_amdgcn_exp2f((s3 - 12.0f) * L2E);
    float ws4 = (p0 + p1) + (p2 + p3);
    #pragma unroll
    for (int o = 1; o < 64; o <<= 1) ws4 += __shfl_xor(ws4, o);
    float pw = (w == 0) ? p0 : (w == 1) ? p1 : (w == 2) ? p2 : p3;
    outb[(size_t)255 * TT + 64 * w + lane] = pw * __builtin_amdgcn_rcpf(ws4);
  }
}

extern "C" void kernel_launch(void* const* d_in, const int* in_sizes, int n_in,
                              void* d_out, int out_size, void* d_ws, size_t ws_size,
                              hipStream_t stream) {
  (void)in_sizes; (void)n_in; (void)d_ws; (void)ws_size; (void)out_size;
  const float* x    = (const float*)d_in[0];
  const float* enc  = (const float*)d_in[1];
  const float* h0   = (const float*)d_in[2];
  const float* c0   = (const float*)d_in[3];
  const float* W1   = (const float*)d_in[4];
  const float* W2   = (const float*)d_in[5];
  const float* V    = (const float*)d_in[6];
  const float* Wk   = (const float*)d_in[7];
  const float* Wr   = (const float*)d_in[8];
  const float* bias = (const float*)d_in[9];
  float* out = (float*)d_out;

  decoder_kernel<<<64, 512, 0, stream>>>(x, enc, h0, c0, W1, W2, V, Wk, Wr, bias, out);
}